// Round 2
// baseline (255.443 us; speedup 1.0000x reference)
//
#include <hip/hip_runtime.h>

// ---------------------------------------------------------------------------
// Problem constants
// ---------------------------------------------------------------------------
#define BATCH   16384
#define NF      16          // N_FEAT
#define OUTD    256         // OUT_DIM
#define NNEW    4828        // generated monomials (deg 2..4)
#define MTOT    4844        // 16 + 4828
#define KPAD    4864        // K padded to 76*64
#define KPAD2   (KPAD/2)
#define NCHUNK  76          // KPAD/64
#define TROW    156         // padded T row (floats): 152 data + 1.0 + 0.0 + pad
#define ASTR    72          // As row stride (ushort): 64 + 8 pad -> 144B rows

// ---------------------------------------------------------------------------
// Compile-time expansion tables
// ---------------------------------------------------------------------------
struct ExpTab { unsigned jp[NNEW]; int off[4]; int total; };

constexpr ExpTab make_tab() {
    ExpTab t{};
    int Id[NF] = {};
    for (int i = 0; i < NF; ++i) Id[i] = i;
    int M = NF, idx = 0;
    for (int pass = 0; pass < 3; ++pass) {
        t.off[pass] = idx;
        const int hi = Id[NF - 1];
        for (int j = 0; j < NF; ++j) {
            const int lo = Id[j];
            for (int p = lo; p <= hi; ++p) t.jp[idx++] = ((unsigned)j << 16) | (unsigned)p;
            Id[j] = M;
            M += hi - lo + 1;
        }
    }
    t.off[3] = idx;
    t.total = M;
    return t;
}
constexpr ExpTab h_tab = make_tab();
static_assert(h_tab.off[1] == 136,  "deg2 count");
static_assert(h_tab.off[2] == 952,  "deg3 end");
static_assert(h_tab.off[3] == NNEW, "total new terms");
static_assert(h_tab.total  == MTOT, "M_TOTAL");

// Packed 3-factor table: every epd column m = T[f0]*T[f1]*T[f2], all f < 154.
//   deg1: (m,152,152)   deg2/3: (j,p,152)   deg4: (j,j3,p3)   pad: (153,153,153)
//   T[152]=1.0, T[153]=0.0. Entry = (4*f0) | (4*f1)<<10 | (4*f2)<<20 (byte offs).
struct PkTab { alignas(16) unsigned e[KPAD]; };

constexpr PkTab make_pk() {
    ExpTab t = make_tab();
    PkTab pk{};
    for (int m = 0; m < KPAD; ++m) {
        int f0, f1, f2;
        if (m < NF)        { f0 = m;   f1 = 152; f2 = 152; }
        else if (m < MTOT) {
            unsigned jp = t.jp[m - NF];
            int j = (int)(jp >> 16), q = (int)(jp & 0xffffu);
            if (q < 152) { f0 = j; f1 = q; f2 = 152; }
            else {
                unsigned jp3 = t.jp[q - NF];           // q in [152,968): a deg3 term
                f0 = j; f1 = (int)(jp3 >> 16); f2 = (int)(jp3 & 0xffffu);
            }
        } else             { f0 = 153; f1 = 153; f2 = 153; }
        pk.e[m] = (unsigned)(4 * f0) | ((unsigned)(4 * f1) << 10) | ((unsigned)(4 * f2) << 20);
    }
    return pk;
}
constexpr bool pk_ok() {                                // deg4 decomposition closes
    ExpTab t = make_tab();
    for (int m = NF; m < MTOT; ++m) {
        unsigned q = t.jp[m - NF] & 0xffffu;
        if (q >= 152) { if ((t.jp[q - NF] & 0xffffu) >= 152) return false; }
    }
    return true;
}
static_assert(pk_ok(), "deg4 factors must reference deg<=2 table");

__device__ const PkTab g_pk = make_pk();

// ---------------------------------------------------------------------------
// Helpers
// ---------------------------------------------------------------------------
typedef __attribute__((ext_vector_type(8))) short    bf16x8;
typedef __attribute__((ext_vector_type(4))) float    f32x4;
typedef __attribute__((ext_vector_type(4))) unsigned uint4v;

__device__ inline unsigned bfpack2(float lo, float hi) {
    unsigned ul = __float_as_uint(lo), uh = __float_as_uint(hi);
    ul = (ul + 0x7fffu + ((ul >> 16) & 1u)) >> 16;
    uh = (uh + 0x7fffu + ((uh >> 16) & 1u)) & 0xffff0000u;
    return ul | uh;
}

// ---------------------------------------------------------------------------
// W fp32 [256][4844] -> bf16 [256][KPAD] (zero-padded)
// ---------------------------------------------------------------------------
__global__ __launch_bounds__(256) void wconv_kernel(
    const float* __restrict__ W, unsigned* __restrict__ Wb)
{
    const int r = blockIdx.x;
    for (int i = threadIdx.x; i < KPAD2; i += 256) {
        const int c0 = 2 * i, c1 = 2 * i + 1;
        const float f0 = (c0 < MTOT) ? W[(size_t)r * MTOT + c0] : 0.f;
        const float f1 = (c1 < MTOT) ? W[(size_t)r * MTOT + c1] : 0.f;
        Wb[(size_t)r * KPAD2 + i] = bfpack2(f0, f1);
    }
}

// ---------------------------------------------------------------------------
// Fused kernel: tanh -> Taylor expansion (on the fly, LDS) -> MFMA GEMM
//   grid 256, 512 thr (8 waves 2x4). BM=64, BN=256, BK=64.
//   A synthesized per chunk into 4-slot rotating LDS; B frags direct from L2,
//   register double-buffered. One barrier per chunk.
// ---------------------------------------------------------------------------
__global__ __launch_bounds__(512, 2) void fused_kernel(
    const float* __restrict__ x,
    const unsigned short* __restrict__ Wb,
    const float* __restrict__ bias,
    float* __restrict__ C)
{
    __shared__ float          T[64][TROW];        // 39.9 KB: deg1+deg2 per row
    __shared__ unsigned short As[4][64][ASTR];    // 36.9 KB: 4-slot A chunks

    const int t   = threadIdx.x;
    const int l   = t & 63;
    const int wid = t >> 6;
    const int wm  = wid >> 2, wn = wid & 3;
    const int lr  = l & 15,  lk = l >> 4;
    const size_t m0 = (size_t)blockIdx.x * 64;
    const unsigned* __restrict__ pk = g_pk.e;

    // --- deg1: tanh(x) + table pads ------------------------------------
    {
#pragma unroll
        for (int i = 0; i < 2; ++i) {
            const int v = t * 2 + i;              // 0..1023
            const int r = v >> 4, f = v & 15;
            T[r][f] = tanhf(x[(m0 + r) * NF + f]);
        }
        const int r = t >> 3, s = t & 7;
        if (s < 4) T[r][152 + s] = (s == 0) ? 1.0f : 0.0f;
    }
    __syncthreads();
    // --- deg2 into T[r][16..151] ---------------------------------------
    {
        const int r = t >> 3, s = t & 7;
        const char* Tr = (const char*)&T[r][0];
#pragma unroll
        for (int i = 0; i < 17; ++i) {
            const int q = s + 8 * i;              // 0..135
            const unsigned e = pk[NF + q];
            const float a = *(const float*)(Tr + (e & 1023u));
            const float b = *(const float*)(Tr + ((e >> 10) & 1023u));
            T[r][NF + q] = a * b;
        }
    }
    __syncthreads();

    // --- per-chunk A expansion: thread t -> row t>>3, 16B slot t&7 ------
    const int er = t >> 3, es = t & 7;
    const char* Tr = (const char*)&T[er][0];
    auto expand = [&](int c, int slot) {
        const uint4v* pp = (const uint4v*)(pk + c * 64 + es * 8);
        const uint4v e0 = pp[0], e1 = pp[1];
        float v[8];
#pragma unroll
        for (int i = 0; i < 8; ++i) {
            const unsigned e = (i < 4) ? e0[i] : e1[i - 4];
            const float a  = *(const float*)(Tr + (e & 1023u));
            const float b  = *(const float*)(Tr + ((e >> 10) & 1023u));
            const float c2 = *(const float*)(Tr + (e >> 20));
            v[i] = a * b * c2;
        }
        uint4v o;
        o[0] = bfpack2(v[0], v[1]); o[1] = bfpack2(v[2], v[3]);
        o[2] = bfpack2(v[4], v[5]); o[3] = bfpack2(v[6], v[7]);
        *(uint4v*)&As[slot][er][es * 8] = o;
    };

    // --- B fragments: direct global (L2-resident W), reg double-buffer --
    const unsigned short* wbase = Wb + (size_t)(wn * 64 + lr) * KPAD + lk * 8;
    bf16x8 bA[4][2], bB[4][2];
    auto prefB = [&](int c, bf16x8 (&bf)[4][2]) {
#pragma unroll
        for (int ni = 0; ni < 4; ++ni)
#pragma unroll
            for (int ks = 0; ks < 2; ++ks)
                bf[ni][ks] = *(const bf16x8*)(wbase + (size_t)ni * 16 * KPAD
                                              + (size_t)c * 64 + ks * 32);
    };

    f32x4 acc[2][4];
#pragma unroll
    for (int i = 0; i < 2; ++i)
#pragma unroll
        for (int j = 0; j < 4; ++j) acc[i][j] = (f32x4){0.f, 0.f, 0.f, 0.f};

    auto domfma = [&](int slot, bf16x8 (&bf)[4][2]) {
#pragma unroll
        for (int ks = 0; ks < 2; ++ks) {
            bf16x8 af[2];
#pragma unroll
            for (int mi = 0; mi < 2; ++mi)
                af[mi] = *(const bf16x8*)&As[slot][wm * 32 + mi * 16 + lr][ks * 32 + lk * 8];
#pragma unroll
            for (int mi = 0; mi < 2; ++mi)
#pragma unroll
                for (int ni = 0; ni < 4; ++ni)
                    acc[mi][ni] = __builtin_amdgcn_mfma_f32_16x16x32_bf16(
                        af[mi], bf[ni][ks], acc[mi][ni], 0, 0, 0);
        }
    };

    // --- main loop: 1 barrier per chunk, 2 chunks per iteration ---------
    prefB(0, bA);
    expand(0, 0);
    __syncthreads();
    for (int it = 0; it < NCHUNK / 2; ++it) {
        const int c = 2 * it;
        prefB(c + 1, bB);
        expand(c + 1, (c + 1) & 3);
        domfma(c & 3, bA);
        __syncthreads();
        if (c + 2 < NCHUNK) {
            prefB(c + 2, bA);
            expand(c + 2, (c + 2) & 3);
        }
        domfma((c + 1) & 3, bB);
        __syncthreads();
    }

    // --- epilogue: bias + relu ------------------------------------------
#pragma unroll
    for (int ni = 0; ni < 4; ++ni) {
        const int col = wn * 64 + ni * 16 + lr;
        const float bv = bias[col];
#pragma unroll
        for (int mi = 0; mi < 2; ++mi) {
            const size_t r0 = m0 + wm * 32 + mi * 16 + lk * 4;
#pragma unroll
            for (int j = 0; j < 4; ++j)
                C[(r0 + j) * OUTD + col] = fmaxf(acc[mi][ni][j] + bv, 0.f);
        }
    }
}

// ---------------------------------------------------------------------------
// Launch
// ---------------------------------------------------------------------------
extern "C" void kernel_launch(void* const* d_in, const int* in_sizes, int n_in,
                              void* d_out, int out_size, void* d_ws, size_t ws_size,
                              hipStream_t stream)
{
    const float* x    = (const float*)d_in[0];   // [16384,16,1]
    const float* W    = (const float*)d_in[1];   // [256,4844]
    const float* bias = (const float*)d_in[2];   // [256,1]
    float* out        = (float*)d_out;           // [16384,256,1]

    unsigned* Wb = (unsigned*)d_ws;              // 2.49 MB bf16 W copy
    wconv_kernel<<<OUTD, 256, 0, stream>>>(W, Wb);
    fused_kernel<<<BATCH / 64, 512, 0, stream>>>(
        x, (const unsigned short*)Wb, bias, out);
}

// Round 4
// 148.858 us; speedup vs baseline: 1.7160x; 1.7160x over previous
//
#include <hip/hip_runtime.h>

// ---------------------------------------------------------------------------
// Problem constants
// ---------------------------------------------------------------------------
#define BATCH   16384
#define NF      16          // N_FEAT
#define OUTD    256         // OUT_DIM
#define NNEW    4828        // generated monomials (deg 2..4)
#define MTOT    4844        // 16 + 4828
#define KPAD    4864        // 76 * 64
#define KPAD2   (KPAD/2)
#define NCHUNK  76
#define TROW    155         // T row stride in floats: 27 mod 32 -> conflict-free strided gathers
#define ASTR    72          // As row stride (ushort): 144 B, 16B-aligned

// ---------------------------------------------------------------------------
// Compile-time expansion tables
// ---------------------------------------------------------------------------
struct ExpTab { unsigned jp[NNEW]; int total; };

constexpr ExpTab make_tab() {
    ExpTab t{};
    int Id[NF] = {};
    for (int i = 0; i < NF; ++i) Id[i] = i;
    int M = NF, idx = 0;
    for (int pass = 0; pass < 3; ++pass) {
        const int hi = Id[NF - 1];
        for (int j = 0; j < NF; ++j) {
            const int lo = Id[j];
            for (int p = lo; p <= hi; ++p) t.jp[idx++] = ((unsigned)j << 16) | (unsigned)p;
            Id[j] = M;
            M += hi - lo + 1;
        }
    }
    t.total = M;
    return t;
}
constexpr ExpTab h_tab = make_tab();
static_assert(h_tab.total == MTOT, "M_TOTAL");

// 2-factor table: epd[m] = T2[L]*T2[R], T2 = {16 deg1, 136 deg2, [152]=1, [153]=0}
//   deg1:(m,152)  deg2:(d2[a][b],152)  deg3:(d2[a][b],c)  deg4:(d2[a][b],d2[c][d])
struct PkTab {
    alignas(16) unsigned e[KPAD];   // L | R<<16  (word offsets within a T row)
    unsigned b2[136];               // j | p<<16  (deg1 offsets, to build deg2)
};

constexpr PkTab make_pk() {
    ExpTab t = make_tab();
    int d2[NF][NF] = {};
    {
        int m = NF;
        for (int j = 0; j < NF; ++j)
            for (int p = j; p < NF; ++p) d2[j][p] = m++;
    }
    PkTab pk{};
    for (int q = 0; q < 136; ++q) {
        unsigned jp = t.jp[q];
        pk.b2[q] = (jp >> 16) | ((jp & 0xffffu) << 16);
    }
    for (int m = 0; m < KPAD; ++m) {
        if (m >= MTOT) { pk.e[m] = 153u | (153u << 16); continue; }
        int f[4] = {}, n = 0, cur = m;
        while (cur >= NF) {                       // peel j factors down to deg1
            unsigned jp = t.jp[cur - NF];
            f[n++] = (int)(jp >> 16);
            cur = (int)(jp & 0xffffu);
        }
        f[n++] = cur;
        for (int i = 0; i < n; ++i)               // sort
            for (int k = i + 1; k < n; ++k)
                if (f[k] < f[i]) { int tmp = f[i]; f[i] = f[k]; f[k] = tmp; }
        unsigned L, R;
        if      (n == 1) { L = (unsigned)f[0];         R = 152u; }
        else if (n == 2) { L = (unsigned)d2[f[0]][f[1]]; R = 152u; }
        else if (n == 3) { L = (unsigned)d2[f[0]][f[1]]; R = (unsigned)f[2]; }
        else             { L = (unsigned)d2[f[0]][f[1]]; R = (unsigned)d2[f[2]][f[3]]; }
        pk.e[m] = L | (R << 16);
    }
    return pk;
}
constexpr bool pk_ok() {
    PkTab p = make_pk();
    for (int m = 0; m < KPAD; ++m)
        if ((p.e[m] & 0xffffu) > 153u || (p.e[m] >> 16) > 153u) return false;
    return p.e[16] == (16u | (152u << 16));       // x0^2 sanity
}
static_assert(pk_ok(), "2-factor decomposition");

__device__ const PkTab g_pk = make_pk();

// ---------------------------------------------------------------------------
// Helpers
// ---------------------------------------------------------------------------
typedef __attribute__((ext_vector_type(8))) short    bf16x8;
typedef __attribute__((ext_vector_type(4))) float    f32x4;
typedef __attribute__((ext_vector_type(4))) unsigned uint4v;

__device__ inline unsigned bfpack2(float lo, float hi) {
    unsigned ul = __float_as_uint(lo), uh = __float_as_uint(hi);
    ul = (ul + 0x7fffu + ((ul >> 16) & 1u)) >> 16;
    uh = (uh + 0x7fffu + ((uh >> 16) & 1u)) & 0xffff0000u;
    return ul | uh;
}

// ---------------------------------------------------------------------------
// W fp32 [256][4844] -> bf16 [256][KPAD] (zero-padded)
// ---------------------------------------------------------------------------
__global__ __launch_bounds__(256) void wconv_kernel(
    const float* __restrict__ W, unsigned* __restrict__ Wb)
{
    const int r = blockIdx.x;
    for (int i = threadIdx.x; i < KPAD2; i += 256) {
        const int c0 = 2 * i, c1 = 2 * i + 1;
        const float f0 = (c0 < MTOT) ? W[(size_t)r * MTOT + c0] : 0.f;
        const float f1 = (c1 < MTOT) ? W[(size_t)r * MTOT + c1] : 0.f;
        Wb[(size_t)r * KPAD2 + i] = bfpack2(f0, f1);
    }
}

// ---------------------------------------------------------------------------
// Fused: tanh -> expansion (producer waves 0-3) -> MFMA GEMM (consumer 4-7)
//   BM=64, BN=256, BK=64, grid 256, 512 thr. 2-slot As double buffer,
//   one barrier per half-iteration (= per chunk).
// ---------------------------------------------------------------------------
__global__ __launch_bounds__(512, 2) void fused_kernel(
    const float* __restrict__ x,
    const unsigned short* __restrict__ Wb,
    const float* __restrict__ bias,
    float* __restrict__ C)
{
    __shared__ float T[64 * TROW];                       // 39.7 KB
    __shared__ alignas(16) unsigned short As[2][64][ASTR]; // 18.4 KB
    const int t   = threadIdx.x;
    const int l   = t & 63;
    const int wid = t >> 6;
    const size_t m0 = (size_t)blockIdx.x * 64;

    // producer pk prefetch buffers (issued before prologue to hide L2 latency)
    uint4v eA[4], eB[4];
    auto loadPk = [&](int c, uint4v (&e4)[4]) {
        const uint4v* pe = (const uint4v*)(g_pk.e + c * 64 + wid * 16);
#pragma unroll
        for (int i = 0; i < 4; ++i) e4[i] = pe[i];
    };
    if (wid < 4) loadPk(0, eA);

    // --- prologue: deg1 (tanh) ------------------------------------------
#pragma unroll
    for (int i = 0; i < 2; ++i) {
        const int v = t * 2 + i;                  // 0..1023
        const int r = v >> 4, fq = v & 15;
        T[r * TROW + fq] = tanhf(x[(m0 + r) * NF + fq]);
    }
    if (t < 64) { T[t * TROW + 152] = 1.0f; T[t * TROW + 153] = 0.0f; }
    __syncthreads();

    // --- deg2 ------------------------------------------------------------
    {
        const int r = t >> 3, s = t & 7, base = r * TROW;
#pragma unroll
        for (int i = 0; i < 17; ++i) {
            const int q = s + 8 * i;              // 0..135
            const unsigned e = g_pk.b2[q];
            T[base + NF + q] = T[base + (e & 0xffffu)] * T[base + (e >> 16)];
        }
    }
    __syncthreads();

    // --- producer: expand 16 cols (wave slice) for own row (lane = row) --
    const int pbase = l * TROW;
    auto expand = [&](int slot, const uint4v (&e4)[4]) {
        float v[16];
#pragma unroll
        for (int i = 0; i < 16; ++i) {
            const unsigned e = e4[i >> 2][i & 3]; // wave-uniform offsets
            v[i] = T[pbase + (e & 0xffffu)] * T[pbase + (e >> 16)];
        }
        uint4v o0, o1;
        o0[0] = bfpack2(v[0],  v[1]);  o0[1] = bfpack2(v[2],  v[3]);
        o0[2] = bfpack2(v[4],  v[5]);  o0[3] = bfpack2(v[6],  v[7]);
        o1[0] = bfpack2(v[8],  v[9]);  o1[1] = bfpack2(v[10], v[11]);
        o1[2] = bfpack2(v[12], v[13]); o1[3] = bfpack2(v[14], v[15]);
        *(uint4v*)&As[slot][l][wid * 16]     = o0;
        *(uint4v*)&As[slot][l][wid * 16 + 8] = o1;
    };

    // --- consumer state --------------------------------------------------
    const int w  = wid - 4;
    const int lr = l & 15, lk = l >> 4;
    const unsigned short* wbase = Wb + (size_t)(w * 64 + lr) * KPAD + lk * 8;
    bf16x8 bA[4][2], bB[4][2];
    auto prefB = [&](int c, bf16x8 (&bf)[4][2]) {
#pragma unroll
        for (int ni = 0; ni < 4; ++ni)
#pragma unroll
            for (int ks = 0; ks < 2; ++ks)
                bf[ni][ks] = *(const bf16x8*)(wbase + (size_t)ni * 16 * KPAD
                                              + (size_t)c * 64 + ks * 32);
    };
    f32x4 acc[4][4];
#pragma unroll
    for (int i = 0; i < 4; ++i)
#pragma unroll
        for (int j = 0; j < 4; ++j) acc[i][j] = (f32x4){0.f, 0.f, 0.f, 0.f};

    auto domfma = [&](int slot, bf16x8 (&bf)[4][2]) {
#pragma unroll
        for (int ks = 0; ks < 2; ++ks) {
            bf16x8 af[4];
#pragma unroll
            for (int mi = 0; mi < 4; ++mi)
                af[mi] = *(const bf16x8*)&As[slot][mi * 16 + lr][ks * 32 + lk * 8];
#pragma unroll
            for (int mi = 0; mi < 4; ++mi)
#pragma unroll
                for (int ni = 0; ni < 4; ++ni)
                    acc[mi][ni] = __builtin_amdgcn_mfma_f32_16x16x32_bf16(
                        af[mi], bf[ni][ks], acc[mi][ni], 0, 0, 0);
        }
    };

    // --- pre-loop: chunk 0 staged, pk/B prefetch for chunk 1 --------------
    if (wid < 4) { expand(0, eA); loadPk(1, eB); }
    else         { prefB(0, bA); }
    __syncthreads();

    // --- main loop: 2 chunks / iter, 1 barrier / chunk --------------------
    for (int it = 0; it < NCHUNK / 2; ++it) {
        const int c = 2 * it;
        if (wid < 4) {
            if (c + 2 < NCHUNK) loadPk(c + 2, eA);
            expand(1, eB);                        // chunk c+1 -> slot 1
        } else {
            prefB(c + 1, bB);
            domfma(0, bA);                        // chunk c (slot 0)
        }
        __syncthreads();
        if (wid < 4) {
            if (c + 3 < NCHUNK) loadPk(c + 3, eB);
            if (c + 2 < NCHUNK) expand(0, eA);    // chunk c+2 -> slot 0
        } else {
            if (c + 2 < NCHUNK) prefB(c + 2, bA);
            domfma(1, bB);                        // chunk c+1 (slot 1)
        }
        __syncthreads();
    }

    // --- epilogue: consumers store bias+relu ------------------------------
    if (wid >= 4) {
#pragma unroll
        for (int ni = 0; ni < 4; ++ni) {
            const int col = w * 64 + ni * 16 + lr;
            const float bv = bias[col];
#pragma unroll
            for (int mi = 0; mi < 4; ++mi) {
                const size_t r0 = m0 + mi * 16 + lk * 4;
#pragma unroll
                for (int j = 0; j < 4; ++j)
                    C[(r0 + j) * OUTD + col] = fmaxf(acc[mi][ni][j] + bv, 0.f);
            }
        }
    }
}

// ---------------------------------------------------------------------------
// Launch
// ---------------------------------------------------------------------------
extern "C" void kernel_launch(void* const* d_in, const int* in_sizes, int n_in,
                              void* d_out, int out_size, void* d_ws, size_t ws_size,
                              hipStream_t stream)
{
    const float* x    = (const float*)d_in[0];   // [16384,16,1]
    const float* W    = (const float*)d_in[1];   // [256,4844]
    const float* bias = (const float*)d_in[2];   // [256,1]
    float* out        = (float*)d_out;           // [16384,256,1]

    unsigned* Wb = (unsigned*)d_ws;              // 2.49 MB bf16 W copy
    wconv_kernel<<<OUTD, 256, 0, stream>>>(W, Wb);
    fused_kernel<<<BATCH / 64, 512, 0, stream>>>(
        x, (const unsigned short*)Wb, bias, out);
}